// Round 1
// baseline (815.557 us; speedup 1.0000x reference)
//
#include <hip/hip_runtime.h>
#include <hip/hip_bf16.h>
#include <math.h>

// ---------- types ----------
typedef __bf16 bf16_8 __attribute__((ext_vector_type(8)));
typedef __bf16 bf16_4 __attribute__((ext_vector_type(4)));
typedef float  f32x4  __attribute__((ext_vector_type(4)));

static __device__ __forceinline__ float sigmoidf_(float x){ return 1.0f/(1.0f + expf(-x)); }

// ---------- problem constants ----------
// L=2, B=128, H=1024, S=512, V=32000, D=64
#define BB 128
#define HH 1024
#define SS 512
#define VV 32000

// ---------- workspace layout (bytes) ----------
#define OFF_A0    0u            // bf16 [128][2048]  (x_emb | h_in0)
#define OFF_A1    524288u       // bf16 [128][2048]  (h_new0 | h_in1)
#define OFF_ALOG  1048576u      // bf16 [128][1024]  h_new1
#define OFF_AH    1310720u      // bf16 [128][1024]  h_top hi
#define OFF_AM    1572864u      // bf16 [128][1024]  h_top mid
#define OFF_AL    1835008u      // bf16 [128][1024]  h_top lo
#define OFF_WAT   2097152u      // f32  [1024][1024] W_a^T
#define OFF_Q     6291456u      // f32  [128][1024]  q
#define OFF_PACC  6815744u      // f32  [128]
#define OFF_PT    6816256u      // f32  [128]
#define OFF_SI    6816768u      // i32  [128]
#define OFF_SC    6817280u      // f32  [128][132]   scores
#define OFF_AT    6884864u      // f32  [128][132]   a_t
#define OFF_GATES 6952448u      // f32  [128][4096]
#define OFF_PLOG  9049600u      // f32  [128][32000]

// ---------- W_a transpose (fp32 -> fp32, [k][n] -> [n][k]) ----------
__global__ void k_transpose(const float* __restrict__ in, float* __restrict__ out){
  __shared__ float t[32][33];
  int kt = blockIdx.x, nt = blockIdx.y;
  int c = threadIdx.x & 31, r0 = threadIdx.x >> 5;
  #pragma unroll
  for (int i = 0; i < 4; ++i){
    int r = r0 + 8*i;
    t[r][c] = in[(size_t)(kt*32 + r)*HH + nt*32 + c];
  }
  __syncthreads();
  #pragma unroll
  for (int i = 0; i < 4; ++i){
    int r = r0 + 8*i;
    out[(size_t)(nt*32 + r)*HH + kt*32 + c] = t[c][r];
  }
}

// ---------- prep: emb gather -> A0 low, h_top 3-split, bias sums, p_acc zero ----------
__global__ void k_prep(const int* __restrict__ ids, const float* __restrict__ emb,
                       const float* __restrict__ h,
                       const float* __restrict__ b_ih, const float* __restrict__ b_hh,
                       __bf16* __restrict__ A0, __bf16* __restrict__ Ah,
                       __bf16* __restrict__ Am, __bf16* __restrict__ Al,
                       float* __restrict__ p_acc, float* __restrict__ bsum0,
                       float* __restrict__ bsum1){
  int blk = blockIdx.x, t = threadIdx.x;
  if (blk < BB){
    int b = blk, c = t*4;
    int tok = ids[b];
    f32x4 e = *(const f32x4*)(emb + (size_t)tok*HH + c);
    bf16_4 e4; 
    #pragma unroll
    for (int i=0;i<4;i++) e4[i] = (__bf16)e[i];
    *(bf16_4*)(A0 + (size_t)b*2048 + c) = e4;
    f32x4 x = *(const f32x4*)(h + (size_t)BB*HH + (size_t)b*HH + c); // h[1]
    bf16_4 hi4, mi4, lo4;
    #pragma unroll
    for (int i=0;i<4;i++){
      float v = x[i];
      __bf16 bh = (__bf16)v; float r1 = v - (float)bh;
      __bf16 bm = (__bf16)r1; float r2 = r1 - (float)bm;
      hi4[i]=bh; mi4[i]=bm; lo4[i]=(__bf16)r2;
    }
    *(bf16_4*)(Ah + (size_t)b*HH + c) = hi4;
    *(bf16_4*)(Am + (size_t)b*HH + c) = mi4;
    *(bf16_4*)(Al + (size_t)b*HH + c) = lo4;
    if (b == 0 && t < BB) p_acc[t] = 0.f;
  } else if (blk == BB){
    for (int i=t; i<4096; i+=256) bsum0[i] = b_ih[i] + b_hh[i];
  } else {
    for (int i=t; i<4096; i+=256) bsum1[i] = b_ih[4096+i] + b_hh[4096+i];
  }
}

// ---------- generic MFMA GEMM: C[128,N] = A[128,K] * B^T (+bias), weights fp32->bf16 in-reg ----------
// PREC: 1 = plain bf16, 2 = hi/lo (3 products), 3 = hi/mid/lo (6 products)
// EPI:  0 = store C (+bias), 1 = tanh(z+bias)*v_pt atomic-reduced into p_acc[m]
template<int PREC, int EPI>
__global__ __launch_bounds__(256) void k_gemm(
    const __bf16* __restrict__ Ah, const __bf16* __restrict__ Am, const __bf16* __restrict__ Al,
    int lda,
    const float* __restrict__ B1, const float* __restrict__ B2, int K1, int K2,
    const float* __restrict__ bias,
    float* __restrict__ C, int N,
    const float* __restrict__ v_pt, float* __restrict__ p_acc)
{
  constexpr int NS  = PREC;
  constexpr int BK  = (PREC == 1) ? 64 : 32;
  constexpr int KG  = BK/8;            // 16B groups per row
  constexpr int TILE = 128*BK*2;       // bytes per tile
  constexpr int UPT = (128*KG)/256;    // staging units per thread
  __shared__ __align__(16) char smem[NS*2*TILE];
  char* sA = smem;
  char* sB = smem + NS*TILE;

  const int t = threadIdx.x;
  const int lane = t & 63, wave = t >> 6;
  const int wm = wave >> 1, wn = wave & 1;
  const int quad = lane >> 4, ln = lane & 15;
  const int nblock = blockIdx.x * 128;
  const int K = K1 + K2;

  f32x4 acc[4][4];
  #pragma unroll
  for (int i=0;i<4;i++)
    #pragma unroll
    for (int j=0;j<4;j++) acc[i][j] = f32x4{0.f,0.f,0.f,0.f};

  for (int k0 = 0; k0 < K; k0 += BK){
    // ---- stage A (bf16 copies) and B (fp32 -> bf16 split) ----
    #pragma unroll
    for (int i = 0; i < UPT; ++i){
      int u = t + 256*i;
      int row = u / KG, kg = u % KG;
      int sl = row*(BK*2) + (((kg ^ (row & (KG-1)))) << 4);
      { // A
        *(uint4*)(sA + sl) = *(const uint4*)(Ah + (size_t)row*lda + k0 + kg*8);
        if constexpr (PREC >= 2)
          *(uint4*)(sA + TILE + sl) = *(const uint4*)(Am + (size_t)row*lda + k0 + kg*8);
        if constexpr (PREC >= 3)
          *(uint4*)(sA + 2*TILE + sl) = *(const uint4*)(Al + (size_t)row*lda + k0 + kg*8);
      }
      { // B
        int ng = nblock + row;
        const float* src = (k0 < K1) ? (B1 + (size_t)ng*K1 + k0 + kg*8)
                                     : (B2 + (size_t)ng*K2 + (k0 - K1) + kg*8);
        f32x4 x0 = *(const f32x4*)(src);
        f32x4 x1 = *(const f32x4*)(src + 4);
        bf16_8 hi, mi, lo;
        #pragma unroll
        for (int q=0;q<8;q++){
          float v = (q<4) ? x0[q] : x1[q-4];
          __bf16 bh = (__bf16)v;
          hi[q] = bh;
          if constexpr (PREC >= 2){
            float r1 = v - (float)bh;
            __bf16 bm = (__bf16)r1;
            mi[q] = bm;
            if constexpr (PREC >= 3) lo[q] = (__bf16)(r1 - (float)bm);
          }
        }
        *(bf16_8*)(sB + sl) = hi;
        if constexpr (PREC >= 2) *(bf16_8*)(sB + TILE + sl) = mi;
        if constexpr (PREC >= 3) *(bf16_8*)(sB + 2*TILE + sl) = lo;
      }
    }
    __syncthreads();
    // ---- MFMA ----
    #pragma unroll
    for (int ks = 0; ks < BK/32; ++ks){
      bf16_8 af[NS][4], bfr[NS][4];
      #pragma unroll
      for (int mt=0; mt<4; ++mt){
        int row = wm*64 + mt*16 + ln;
        int kg = ks*4 + quad;
        int sl = row*(BK*2) + (((kg ^ (row & (KG-1)))) << 4);
        #pragma unroll
        for (int s=0;s<NS;s++) af[s][mt] = *(const bf16_8*)(sA + s*TILE + sl);
      }
      #pragma unroll
      for (int nt=0; nt<4; ++nt){
        int row = wn*64 + nt*16 + ln;
        int kg = ks*4 + quad;
        int sl = row*(BK*2) + (((kg ^ (row & (KG-1)))) << 4);
        #pragma unroll
        for (int s=0;s<NS;s++) bfr[s][nt] = *(const bf16_8*)(sB + s*TILE + sl);
      }
      #pragma unroll
      for (int mt=0; mt<4; ++mt)
        #pragma unroll
        for (int nt=0; nt<4; ++nt){
          acc[mt][nt] = __builtin_amdgcn_mfma_f32_16x16x32_bf16(af[0][mt], bfr[0][nt], acc[mt][nt], 0,0,0);
          if constexpr (PREC >= 2){
            acc[mt][nt] = __builtin_amdgcn_mfma_f32_16x16x32_bf16(af[0][mt], bfr[1][nt], acc[mt][nt], 0,0,0);
            acc[mt][nt] = __builtin_amdgcn_mfma_f32_16x16x32_bf16(af[1][mt], bfr[0][nt], acc[mt][nt], 0,0,0);
          }
          if constexpr (PREC >= 3){
            acc[mt][nt] = __builtin_amdgcn_mfma_f32_16x16x32_bf16(af[0][mt], bfr[2][nt], acc[mt][nt], 0,0,0);
            acc[mt][nt] = __builtin_amdgcn_mfma_f32_16x16x32_bf16(af[1][mt], bfr[1][nt], acc[mt][nt], 0,0,0);
            acc[mt][nt] = __builtin_amdgcn_mfma_f32_16x16x32_bf16(af[2][mt], bfr[0][nt], acc[mt][nt], 0,0,0);
          }
        }
    }
    __syncthreads();
  }

  // ---- epilogue ----
  if constexpr (EPI == 0){
    #pragma unroll
    for (int nt=0; nt<4; ++nt){
      int n = nblock + wn*64 + nt*16 + ln;
      float bv = bias ? bias[n] : 0.f;
      #pragma unroll
      for (int mt=0; mt<4; ++mt){
        int m0 = wm*64 + mt*16 + quad*4;
        #pragma unroll
        for (int r=0;r<4;++r)
          C[(size_t)(m0 + r)*N + n] = acc[mt][nt][r] + bv;
      }
    }
  } else {
    float pv[16];
    #pragma unroll
    for (int i=0;i<16;i++) pv[i]=0.f;
    #pragma unroll
    for (int nt=0; nt<4; ++nt){
      int n = nblock + wn*64 + nt*16 + ln;
      float bv = bias[n], vv = v_pt[n];
      #pragma unroll
      for (int mt=0; mt<4; ++mt)
        #pragma unroll
        for (int r=0;r<4;++r)
          pv[mt*4+r] += tanhf(acc[mt][nt][r] + bv) * vv;
    }
    #pragma unroll
    for (int i=0;i<16;i++){
      float v = pv[i];
      v += __shfl_xor(v, 1); v += __shfl_xor(v, 2);
      v += __shfl_xor(v, 4); v += __shfl_xor(v, 8);
      pv[i] = v;
    }
    if (ln == 0){
      #pragma unroll
      for (int mt=0;mt<4;++mt)
        #pragma unroll
        for (int r=0;r<4;++r)
          atomicAdd(p_acc + wm*64 + mt*16 + quad*4 + r, pv[mt*4+r]);
    }
  }
}

// ---------- p_t / s ----------
__global__ void k_s(const float* __restrict__ p_acc, const float* __restrict__ b_v,
                    float* __restrict__ p_t, int* __restrict__ s_i, float* __restrict__ out_s){
  int t = threadIdx.x;
  float z = p_acc[t] + b_v[0];
  float p = (float)SS * sigmoidf_(z);
  float sf = rintf(p);
  sf = fminf(fmaxf(sf, 64.0f), 447.0f);
  p_t[t] = p; s_i[t] = (int)sf; out_s[t] = sf;
}

// ---------- scores: wave per (b, j) ----------
__global__ void k_scores(const float* __restrict__ q, const float* __restrict__ h_s,
                         const int* __restrict__ s_i, const float* __restrict__ b_a,
                         float* __restrict__ sc){
  int b = blockIdx.x;
  int jj = blockIdx.y*4 + (threadIdx.x >> 6);
  if (jj >= 129) return;
  int lane = threadIdx.x & 63;
  int pos = s_i[b] - 64 + jj;
  const float* row = h_s + ((size_t)pos*BB + b)*HH;
  const float* qb  = q + (size_t)b*HH;
  f32x4 a = f32x4{0.f,0.f,0.f,0.f};
  #pragma unroll
  for (int c = lane*4; c < HH; c += 256){
    f32x4 r4 = *(const f32x4*)(row + c);
    f32x4 q4 = *(const f32x4*)(qb + c);
    a += r4*q4;
  }
  float s = a[0]+a[1]+a[2]+a[3];
  #pragma unroll
  for (int m=1;m<64;m<<=1) s += __shfl_xor(s, m);
  if (lane == 0) sc[b*132 + jj] = s + b_a[0];
}

// ---------- softmax * gauss ----------
__global__ void k_softmax(const float* __restrict__ sc, const int* __restrict__ s_i,
                          const float* __restrict__ p_t, float* __restrict__ a_t){
  int b = blockIdx.x, l = threadIdx.x;
  const float* scb = sc + b*132;
  float mx = -1e30f;
  for (int j=l; j<129; j+=64) mx = fmaxf(mx, scb[j]);
  #pragma unroll
  for (int m=1;m<64;m<<=1) mx = fmaxf(mx, __shfl_xor(mx, m));
  float sum = 0.f;
  for (int j=l; j<129; j+=64) sum += expf(scb[j] - mx);
  #pragma unroll
  for (int m=1;m<64;m<<=1) sum += __shfl_xor(sum, m);
  float inv = 1.0f/sum;
  float pt = p_t[b]; float s0 = (float)(s_i[b] - 64);
  for (int j=l; j<129; j+=64){
    float e = expf(scb[j]-mx)*inv;
    float d = (s0 + (float)j) - pt;
    a_t[b*132 + j] = e * expf(-(d*d) * (1.0f/2048.0f));
  }
}

// ---------- context + h_in epilogue ----------
__global__ void k_context(const float* __restrict__ a_t, const float* __restrict__ h_s,
                          const int* __restrict__ s_i, const float* __restrict__ h,
                          float* __restrict__ ctx_out, __bf16* __restrict__ A0,
                          __bf16* __restrict__ A1){
  int b = blockIdx.x >> 2;
  int c = (blockIdx.x & 3)*256 + threadIdx.x*4;
  const float* base = h_s + ((size_t)(s_i[b]-64)*BB + b)*HH + c;
  const float* ab = a_t + b*132;
  f32x4 acc = f32x4{0.f,0.f,0.f,0.f};
  for (int j=0;j<129;++j){
    f32x4 r = *(const f32x4*)(base + (size_t)j*BB*HH);
    acc += r * ab[j];
  }
  *(f32x4*)(ctx_out + (size_t)b*HH + c) = acc;
  f32x4 h0 = *(const f32x4*)(h + (size_t)b*HH + c) + acc;
  f32x4 h1 = *(const f32x4*)(h + (size_t)BB*HH + (size_t)b*HH + c) + acc;
  bf16_4 v0, v1;
  #pragma unroll
  for (int i=0;i<4;i++){ v0[i]=(__bf16)h0[i]; v1[i]=(__bf16)h1[i]; }
  *(bf16_4*)(A0 + (size_t)b*2048 + 1024 + c) = v0;
  *(bf16_4*)(A1 + (size_t)b*2048 + 1024 + c) = v1;
}

// ---------- LSTM cell ----------
__global__ void k_cell(const float* __restrict__ gates, const float* __restrict__ c_in,
                       float* __restrict__ h_out, float* __restrict__ c_out,
                       __bf16* __restrict__ Anext, int strideNext){
  int g = blockIdx.x*256 + threadIdx.x;     // 0..131071
  int b = g >> 10, hc = g & 1023;
  const float* gb = gates + (size_t)b*4096;
  float ig = gb[hc], fg = gb[1024+hc], gg = gb[2048+hc], og = gb[3072+hc];
  float cn = sigmoidf_(fg)*c_in[g] + sigmoidf_(ig)*tanhf(gg);
  float hn = sigmoidf_(og)*tanhf(cn);
  c_out[g] = cn; h_out[g] = hn;
  Anext[(size_t)b*strideNext + hc] = (__bf16)hn;
}

// ---------- log_softmax rows of 32000 ----------
__global__ void k_lse(const float* __restrict__ plog, float* __restrict__ out){
  __shared__ float red[4];
  int b = blockIdx.x, t = threadIdx.x;
  const float* rowp = plog + (size_t)b*VV;
  float mx = -1e30f;
  for (int i = t*4; i < VV; i += 1024){
    f32x4 v = *(const f32x4*)(rowp + i);
    mx = fmaxf(mx, fmaxf(fmaxf(v[0],v[1]), fmaxf(v[2],v[3])));
  }
  #pragma unroll
  for (int m=1;m<64;m<<=1) mx = fmaxf(mx, __shfl_xor(mx, m));
  if ((t&63)==0) red[t>>6] = mx;
  __syncthreads();
  mx = fmaxf(fmaxf(red[0],red[1]), fmaxf(red[2],red[3]));
  float sum = 0.f;
  for (int i=t*4; i<VV; i+=1024){
    f32x4 v = *(const f32x4*)(rowp + i);
    sum += expf(v[0]-mx)+expf(v[1]-mx)+expf(v[2]-mx)+expf(v[3]-mx);
  }
  #pragma unroll
  for (int m=1;m<64;m<<=1) sum += __shfl_xor(sum, m);
  __syncthreads();
  if ((t&63)==0) red[t>>6] = sum;
  __syncthreads();
  float lse = mx + logf(red[0]+red[1]+red[2]+red[3]);
  for (int i=t*4; i<VV; i+=1024){
    f32x4 v = *(const f32x4*)(rowp + i);
    f32x4 o = v - lse;
    *(f32x4*)(out + (size_t)b*VV + i) = o;
  }
}

// ---------- launch ----------
extern "C" void kernel_launch(void* const* d_in, const int* in_sizes, int n_in,
                              void* d_out, int out_size, void* d_ws, size_t ws_size,
                              hipStream_t stream){
  const int*   ids   = (const int*)d_in[0];
  const float* h     = (const float*)d_in[1];
  const float* c     = (const float*)d_in[2];
  const float* h_s   = (const float*)d_in[3];
  const float* emb   = (const float*)d_in[4];
  const float* W_pt  = (const float*)d_in[5];
  const float* b_pt  = (const float*)d_in[6];
  const float* v_pt  = (const float*)d_in[7];
  const float* b_v   = (const float*)d_in[8];
  const float* W_a   = (const float*)d_in[9];
  const float* b_a   = (const float*)d_in[10];
  const float* W_ih  = (const float*)d_in[11];
  const float* W_hh  = (const float*)d_in[12];
  const float* b_ih  = (const float*)d_in[13];
  const float* b_hh  = (const float*)d_in[14];
  const float* W_out = (const float*)d_in[15];
  const float* b_out = (const float*)d_in[16];

  char* ws = (char*)d_ws;
  __bf16* A0   = (__bf16*)(ws + OFF_A0);
  __bf16* A1   = (__bf16*)(ws + OFF_A1);
  __bf16* Alog = (__bf16*)(ws + OFF_ALOG);
  __bf16* Ah   = (__bf16*)(ws + OFF_AH);
  __bf16* Am   = (__bf16*)(ws + OFF_AM);
  __bf16* Al   = (__bf16*)(ws + OFF_AL);
  float* WaT   = (float*)(ws + OFF_WAT);
  float* q     = (float*)(ws + OFF_Q);
  float* p_acc = (float*)(ws + OFF_PACC);
  float* p_t   = (float*)(ws + OFF_PT);
  int*   s_i   = (int*)  (ws + OFF_SI);
  float* sc    = (float*)(ws + OFF_SC);
  float* a_t   = (float*)(ws + OFF_AT);
  float* gates = (float*)(ws + OFF_GATES);
  float* plog  = (float*)(ws + OFF_PLOG);
  float* bsum0 = (float*)(ws + OFF_PLOG + 16384000u);           // reuse tail: 2x4096 f32
  float* bsum1 = bsum0 + 4096;

  float* out        = (float*)d_out;
  float* out_logits = out;                    // [128][32000]
  float* out_h      = out + 4096000;          // [2][128][1024]
  float* out_c      = out + 4358144;
  float* out_ctx    = out + 4620288;
  float* out_s      = out + 4751360;

  k_transpose<<<dim3(32,32), 256, 0, stream>>>(W_a, WaT);
  k_prep<<<130, 256, 0, stream>>>(ids, emb, h, b_ih, b_hh, A0, Ah, Am, Al, p_acc, bsum0, bsum1);
  // q = h_top @ W_a  (2-way split)
  k_gemm<2,0><<<8, 256, 0, stream>>>(Ah, Am, nullptr, 1024, WaT, nullptr, 1024, 0,
                                     nullptr, q, 1024, nullptr, nullptr);
  // p_t chain (3-way split, fused tanh * v_pt reduce)
  k_gemm<3,1><<<8, 256, 0, stream>>>(Ah, Am, Al, 1024, W_pt, nullptr, 1024, 0,
                                     b_pt, nullptr, 1024, v_pt, p_acc);
  k_s<<<1, 128, 0, stream>>>(p_acc, b_v, p_t, s_i, out_s);
  k_scores<<<dim3(128, 33), 256, 0, stream>>>(q, h_s, s_i, b_a, sc);
  k_softmax<<<128, 64, 0, stream>>>(sc, s_i, p_t, a_t);
  k_context<<<512, 64, 0, stream>>>(a_t, h_s, s_i, h, out_ctx, A0, A1);
  // layer 0 gates
  k_gemm<1,0><<<32, 256, 0, stream>>>(A0, nullptr, nullptr, 2048, W_ih, W_hh, 1024, 1024,
                                      bsum0, gates, 4096, nullptr, nullptr);
  k_cell<<<512, 256, 0, stream>>>(gates, c, out_h, out_c, A1, 2048);
  // layer 1 gates
  k_gemm<1,0><<<32, 256, 0, stream>>>(A1, nullptr, nullptr, 2048, W_ih + 4194304, W_hh + 4194304,
                                      1024, 1024, bsum1, gates, 4096, nullptr, nullptr);
  k_cell<<<512, 256, 0, stream>>>(gates, c + 131072, out_h + 131072, out_c + 131072, Alog, 1024);
  // logits
  k_gemm<1,0><<<250, 256, 0, stream>>>(Alog, nullptr, nullptr, 1024, W_out, nullptr, 1024, 0,
                                       b_out, plog, 32000, nullptr, nullptr);
  k_lse<<<128, 256, 0, stream>>>(plog, out_logits);
}

// Round 2
// 646.114 us; speedup vs baseline: 1.2622x; 1.2622x over previous
//
#include <hip/hip_runtime.h>
#include <hip/hip_bf16.h>
#include <math.h>

typedef __bf16 bf16_8 __attribute__((ext_vector_type(8)));
typedef __bf16 bf16_4 __attribute__((ext_vector_type(4)));
typedef float  f32x4  __attribute__((ext_vector_type(4)));

static __device__ __forceinline__ float sigmoidf_(float x){ return 1.0f/(1.0f + expf(-x)); }

#define BB 128
#define HH 1024
#define SS 512
#define VV 32000

// ---------- workspace layout (bytes) ----------
#define OFF_A0    0u            // bf16 [128][2048]
#define OFF_A1    524288u       // bf16 [128][2048]
#define OFF_ALOG  1048576u      // bf16 [128][1024]
#define OFF_AH    1310720u      // bf16 [128][1024]
#define OFF_AM    1572864u
#define OFF_AL    1835008u
#define OFF_WAT   2097152u      // f32 [1024][1024]
#define OFF_Q     6291456u      // f32 [128][1024]
#define OFF_Z     6815744u      // f32 [128][1024]
#define OFF_PT    7340032u      // f32 [128]
#define OFF_SI    7340544u      // i32 [128]
#define OFF_SC    7341056u      // f32 [128][132]
#define OFF_AT    7408640u      // f32 [128][132]
#define OFF_G0    7476224u      // f32 [128][4096]
#define OFF_G1    9573376u      // f32 [128][4096]
#define OFF_PMAX  11670528u     // f32 [250][128]
#define OFF_PSUM  11801600u     // f32 [250][128]
#define OFF_LSE   11932672u     // f32 [128]

// ---------- W_a transpose ----------
__global__ void k_transpose(const float* __restrict__ in, float* __restrict__ out){
  __shared__ float t[32][33];
  int kt = blockIdx.x, nt = blockIdx.y;
  int c = threadIdx.x & 31, r0 = threadIdx.x >> 5;
  #pragma unroll
  for (int i = 0; i < 4; ++i){
    int r = r0 + 8*i;
    t[r][c] = in[(size_t)(kt*32 + r)*HH + nt*32 + c];
  }
  __syncthreads();
  #pragma unroll
  for (int i = 0; i < 4; ++i){
    int r = r0 + 8*i;
    out[(size_t)(nt*32 + r)*HH + kt*32 + c] = t[c][r];
  }
}

// ---------- prep ----------
// blocks 0..127: emb gather -> A0, h_top 3-split, z[b]=b_pt, q[b]=0
// blocks 128..255: gates0[b]=b_ih0+b_hh0, gates1[b]=b_ih1+b_hh1 (bias pre-init for atomic K-split)
__global__ void k_prep(const int* __restrict__ ids, const float* __restrict__ emb,
                       const float* __restrict__ h,
                       const float* __restrict__ b_pt,
                       const float* __restrict__ b_ih, const float* __restrict__ b_hh,
                       __bf16* __restrict__ A0, __bf16* __restrict__ Ah,
                       __bf16* __restrict__ Am, __bf16* __restrict__ Al,
                       float* __restrict__ z, float* __restrict__ q,
                       float* __restrict__ g0, float* __restrict__ g1){
  int blk = blockIdx.x, t = threadIdx.x;
  if (blk < BB){
    int b = blk, c = t*4;
    int tok = ids[b];
    f32x4 e = *(const f32x4*)(emb + (size_t)tok*HH + c);
    bf16_4 e4;
    #pragma unroll
    for (int i=0;i<4;i++) e4[i] = (__bf16)e[i];
    *(bf16_4*)(A0 + (size_t)b*2048 + c) = e4;
    f32x4 x = *(const f32x4*)(h + (size_t)BB*HH + (size_t)b*HH + c); // h[1]
    bf16_4 hi4, mi4, lo4;
    #pragma unroll
    for (int i=0;i<4;i++){
      float v = x[i];
      __bf16 bh = (__bf16)v; float r1 = v - (float)bh;
      __bf16 bm = (__bf16)r1; float r2 = r1 - (float)bm;
      hi4[i]=bh; mi4[i]=bm; lo4[i]=(__bf16)r2;
    }
    *(bf16_4*)(Ah + (size_t)b*HH + c) = hi4;
    *(bf16_4*)(Am + (size_t)b*HH + c) = mi4;
    *(bf16_4*)(Al + (size_t)b*HH + c) = lo4;
    *(f32x4*)(z + (size_t)b*HH + c) = *(const f32x4*)(b_pt + c);
    *(f32x4*)(q + (size_t)b*HH + c) = f32x4{0.f,0.f,0.f,0.f};
  } else {
    int b = blk - BB;
    for (int i=t; i<4096; i+=256){
      g0[(size_t)b*4096 + i] = b_ih[i] + b_hh[i];
      g1[(size_t)b*4096 + i] = b_ih[4096+i] + b_hh[4096+i];
    }
  }
}

// ---------- MFMA GEMM: C[128,N] += / = A[128,K] * B^T ----------
// PREC: 1 = plain bf16 (BK=64, register-prefetch pipelined)
//       2 = hi/mid split (3 products), 3 = hi/mid/lo (6 products)  (BK=32, simple loop)
// EPI:  0 = store C + bias
//       2 = logits: store C + bias into C, emit per-block row (max, sumexp) partials
//       3 = atomicAdd into C (K-split accumulation; bias pre-initialized by caller)
// K-split via gridDim.y.
template<int PREC, int EPI>
__global__ __launch_bounds__(256) void k_gemm(
    const __bf16* __restrict__ Ah, const __bf16* __restrict__ Am, const __bf16* __restrict__ Al,
    int lda,
    const float* __restrict__ B1, const float* __restrict__ B2, int K1, int K2,
    const float* __restrict__ bias,
    float* __restrict__ C, int N,
    float* __restrict__ Pmax, float* __restrict__ Psum)
{
  constexpr int NS  = PREC;
  constexpr int BK  = (PREC == 1) ? 64 : 32;
  constexpr int KG  = BK/8;
  constexpr int TILE = 128*BK*2;
  constexpr int UPT = (128*KG)/256;
  __shared__ __align__(16) char smem[NS*2*TILE];
  char* sA = smem;
  char* sB = smem + NS*TILE;

  const int t = threadIdx.x;
  const int lane = t & 63, wave = t >> 6;
  const int wm = wave >> 1, wn = wave & 1;
  const int quad = lane >> 4, ln = lane & 15;
  const int nblock = blockIdx.x * 128;
  const int K = K1 + K2;
  const int kchunk = K / gridDim.y;
  const int kstart = blockIdx.y * kchunk;
  const int kend = kstart + kchunk;

  f32x4 acc[4][4];
  #pragma unroll
  for (int i=0;i<4;i++)
    #pragma unroll
    for (int j=0;j<4;j++) acc[i][j] = f32x4{0.f,0.f,0.f,0.f};

  if constexpr (PREC == 1){
    // ---- software-pipelined: global loads for tile k+1 in flight during MFMA on tile k ----
    uint4 aR[UPT]; f32x4 bR[UPT][2];
    auto issue = [&](int k0){
      #pragma unroll
      for (int i=0;i<UPT;++i){
        int u = t + 256*i, row = u/KG, kg = u%KG;
        aR[i] = *(const uint4*)(Ah + (size_t)row*lda + k0 + kg*8);
        int ng = nblock + row;
        const float* src = (k0 < K1) ? (B1 + (size_t)ng*K1 + k0 + kg*8)
                                     : (B2 + (size_t)ng*K2 + (k0 - K1) + kg*8);
        bR[i][0] = *(const f32x4*)(src);
        bR[i][1] = *(const f32x4*)(src + 4);
      }
    };
    issue(kstart);
    for (int k0 = kstart; k0 < kend; k0 += BK){
      __syncthreads();
      #pragma unroll
      for (int i=0;i<UPT;++i){
        int u = t + 256*i, row = u/KG, kg = u%KG;
        int sl = row*(BK*2) + (((kg ^ (row & (KG-1)))) << 4);
        *(uint4*)(sA + sl) = aR[i];
        bf16_8 hi;
        #pragma unroll
        for (int q=0;q<8;++q) hi[q] = (__bf16)((q<4) ? bR[i][0][q] : bR[i][1][q-4]);
        *(bf16_8*)(sB + sl) = hi;
      }
      __syncthreads();
      if (k0 + BK < kend) issue(k0 + BK);
      #pragma unroll
      for (int ks = 0; ks < BK/32; ++ks){
        bf16_8 af[4], bfr[4];
        #pragma unroll
        for (int mt=0; mt<4; ++mt){
          int row = wm*64 + mt*16 + ln;
          int kg = ks*4 + quad;
          int sl = row*(BK*2) + (((kg ^ (row & (KG-1)))) << 4);
          af[mt] = *(const bf16_8*)(sA + sl);
        }
        #pragma unroll
        for (int nt=0; nt<4; ++nt){
          int row = wn*64 + nt*16 + ln;
          int kg = ks*4 + quad;
          int sl = row*(BK*2) + (((kg ^ (row & (KG-1)))) << 4);
          bfr[nt] = *(const bf16_8*)(sB + sl);
        }
        #pragma unroll
        for (int mt=0; mt<4; ++mt)
          #pragma unroll
          for (int nt=0; nt<4; ++nt)
            acc[mt][nt] = __builtin_amdgcn_mfma_f32_16x16x32_bf16(af[mt], bfr[nt], acc[mt][nt], 0,0,0);
      }
    }
  } else {
    // ---- precision-split path (small GEMMs) ----
    for (int k0 = kstart; k0 < kend; k0 += BK){
      #pragma unroll
      for (int i = 0; i < UPT; ++i){
        int u = t + 256*i;
        int row = u / KG, kg = u % KG;
        int sl = row*(BK*2) + (((kg ^ (row & (KG-1)))) << 4);
        *(uint4*)(sA + sl) = *(const uint4*)(Ah + (size_t)row*lda + k0 + kg*8);
        if constexpr (PREC >= 2)
          *(uint4*)(sA + TILE + sl) = *(const uint4*)(Am + (size_t)row*lda + k0 + kg*8);
        if constexpr (PREC >= 3)
          *(uint4*)(sA + 2*TILE + sl) = *(const uint4*)(Al + (size_t)row*lda + k0 + kg*8);
        int ng = nblock + row;
        const float* src = B1 + (size_t)ng*K1 + k0 + kg*8;
        f32x4 x0 = *(const f32x4*)(src);
        f32x4 x1 = *(const f32x4*)(src + 4);
        bf16_8 hi, mi, lo;
        #pragma unroll
        for (int q=0;q<8;q++){
          float v = (q<4) ? x0[q] : x1[q-4];
          __bf16 bh = (__bf16)v;
          hi[q] = bh;
          float r1 = v - (float)bh;
          __bf16 bm = (__bf16)r1;
          mi[q] = bm;
          lo[q] = (__bf16)(r1 - (float)bm);
        }
        *(bf16_8*)(sB + sl) = hi;
        if constexpr (PREC >= 2) *(bf16_8*)(sB + TILE + sl) = mi;
        if constexpr (PREC >= 3) *(bf16_8*)(sB + 2*TILE + sl) = lo;
      }
      __syncthreads();
      #pragma unroll
      for (int ks = 0; ks < BK/32; ++ks){
        bf16_8 af[NS][4], bfr[NS][4];
        #pragma unroll
        for (int mt=0; mt<4; ++mt){
          int row = wm*64 + mt*16 + ln;
          int kg = ks*4 + quad;
          int sl = row*(BK*2) + (((kg ^ (row & (KG-1)))) << 4);
          #pragma unroll
          for (int s=0;s<NS;s++) af[s][mt] = *(const bf16_8*)(sA + s*TILE + sl);
        }
        #pragma unroll
        for (int nt=0; nt<4; ++nt){
          int row = wn*64 + nt*16 + ln;
          int kg = ks*4 + quad;
          int sl = row*(BK*2) + (((kg ^ (row & (KG-1)))) << 4);
          #pragma unroll
          for (int s=0;s<NS;s++) bfr[s][nt] = *(const bf16_8*)(sB + s*TILE + sl);
        }
        #pragma unroll
        for (int mt=0; mt<4; ++mt)
          #pragma unroll
          for (int nt=0; nt<4; ++nt){
            acc[mt][nt] = __builtin_amdgcn_mfma_f32_16x16x32_bf16(af[0][mt], bfr[0][nt], acc[mt][nt], 0,0,0);
            if constexpr (PREC >= 2){
              acc[mt][nt] = __builtin_amdgcn_mfma_f32_16x16x32_bf16(af[0][mt], bfr[1][nt], acc[mt][nt], 0,0,0);
              acc[mt][nt] = __builtin_amdgcn_mfma_f32_16x16x32_bf16(af[1][mt], bfr[0][nt], acc[mt][nt], 0,0,0);
            }
            if constexpr (PREC >= 3){
              acc[mt][nt] = __builtin_amdgcn_mfma_f32_16x16x32_bf16(af[0][mt], bfr[2][nt], acc[mt][nt], 0,0,0);
              acc[mt][nt] = __builtin_amdgcn_mfma_f32_16x16x32_bf16(af[1][mt], bfr[1][nt], acc[mt][nt], 0,0,0);
              acc[mt][nt] = __builtin_amdgcn_mfma_f32_16x16x32_bf16(af[2][mt], bfr[0][nt], acc[mt][nt], 0,0,0);
            }
          }
      }
      __syncthreads();
    }
  }

  // ---- epilogues ----
  if constexpr (EPI == 0){
    #pragma unroll
    for (int nt=0; nt<4; ++nt){
      int n = nblock + wn*64 + nt*16 + ln;
      float bv = bias ? bias[n] : 0.f;
      #pragma unroll
      for (int mt=0; mt<4; ++mt){
        int m0 = wm*64 + mt*16 + quad*4;
        #pragma unroll
        for (int r=0;r<4;++r)
          C[(size_t)(m0 + r)*N + n] = acc[mt][nt][r] + bv;
      }
    }
  } else if constexpr (EPI == 3){
    #pragma unroll
    for (int nt=0; nt<4; ++nt){
      int n = nblock + wn*64 + nt*16 + ln;
      #pragma unroll
      for (int mt=0; mt<4; ++mt){
        int m0 = wm*64 + mt*16 + quad*4;
        #pragma unroll
        for (int r=0;r<4;++r)
          atomicAdd(C + (size_t)(m0 + r)*N + n, acc[mt][nt][r]);
      }
    }
  } else if constexpr (EPI == 2){
    __syncthreads();                         // LDS reuse for reductions
    float* redm = (float*)smem;              // [2][128]
    float* reds = (float*)smem + 256;        // [2][128]
    // per-(mt,r) row max over this wave's 64 columns
    float rmax[16];
    #pragma unroll
    for (int mt=0; mt<4; ++mt)
      #pragma unroll
      for (int r=0;r<4;++r){
        float m4 = -1e30f;
        #pragma unroll
        for (int nt=0;nt<4;++nt){
          int n = nblock + wn*64 + nt*16 + ln;
          m4 = fmaxf(m4, acc[mt][nt][r] + bias[n]);
        }
        #pragma unroll
        for (int m=1;m<16;m<<=1) m4 = fmaxf(m4, __shfl_xor(m4, m));
        rmax[mt*4+r] = m4;
      }
    if (ln == 0){
      #pragma unroll
      for (int mt=0;mt<4;++mt)
        #pragma unroll
        for (int r=0;r<4;++r)
          redm[wn*128 + wm*64 + mt*16 + quad*4 + r] = rmax[mt*4+r];
    }
    __syncthreads();
    // store C; per-row sumexp against combined row max
    #pragma unroll
    for (int mt=0; mt<4; ++mt)
      #pragma unroll
      for (int r=0;r<4;++r){
        int row = wm*64 + mt*16 + quad*4 + r;
        float M = fmaxf(redm[row], redm[128 + row]);
        float s4 = 0.f;
        #pragma unroll
        for (int nt=0;nt<4;++nt){
          int n = nblock + wn*64 + nt*16 + ln;
          float v = acc[mt][nt][r] + bias[n];
          C[(size_t)row*N + n] = v;
          s4 += expf(v - M);
        }
        #pragma unroll
        for (int m=1;m<16;m<<=1) s4 += __shfl_xor(s4, m);
        if (ln == 0) reds[wn*128 + row] = s4;
      }
    __syncthreads();
    if (wn == 0 && ln == 0){
      #pragma unroll
      for (int mt=0;mt<4;++mt)
        #pragma unroll
        for (int r=0;r<4;++r){
          int row = wm*64 + mt*16 + quad*4 + r;
          float M = fmaxf(redm[row], redm[128 + row]);
          Pmax[(size_t)blockIdx.x*128 + row] = M;
          Psum[(size_t)blockIdx.x*128 + row] = reds[row] + reds[128 + row];
        }
    }
  }
}

// ---------- p_t reduce + s ----------
__global__ void k_s2(const float* __restrict__ z, const float* __restrict__ v_pt,
                     const float* __restrict__ b_v,
                     float* __restrict__ p_t, int* __restrict__ s_i, float* __restrict__ out_s){
  __shared__ float red[4];
  int b = blockIdx.x, t = threadIdx.x;
  f32x4 zv = *(const f32x4*)(z + (size_t)b*HH + t*4);
  f32x4 vv = *(const f32x4*)(v_pt + t*4);
  float s = tanhf(zv[0])*vv[0] + tanhf(zv[1])*vv[1] + tanhf(zv[2])*vv[2] + tanhf(zv[3])*vv[3];
  #pragma unroll
  for (int m=1;m<64;m<<=1) s += __shfl_xor(s, m);
  if ((t&63)==0) red[t>>6] = s;
  __syncthreads();
  if (t == 0){
    float tot = red[0]+red[1]+red[2]+red[3] + b_v[0];
    float p = (float)SS * sigmoidf_(tot);
    float sf = rintf(p);
    sf = fminf(fmaxf(sf, 64.0f), 447.0f);
    p_t[b] = p; s_i[b] = (int)sf; out_s[b] = sf;
  }
}

// ---------- scores ----------
__global__ void k_scores(const float* __restrict__ q, const float* __restrict__ h_s,
                         const int* __restrict__ s_i, const float* __restrict__ b_a,
                         float* __restrict__ sc){
  int b = blockIdx.x;
  int jj = blockIdx.y*4 + (threadIdx.x >> 6);
  if (jj >= 129) return;
  int lane = threadIdx.x & 63;
  int pos = s_i[b] - 64 + jj;
  const float* row = h_s + ((size_t)pos*BB + b)*HH;
  const float* qb  = q + (size_t)b*HH;
  f32x4 a = f32x4{0.f,0.f,0.f,0.f};
  #pragma unroll
  for (int c = lane*4; c < HH; c += 256){
    f32x4 r4 = *(const f32x4*)(row + c);
    f32x4 q4 = *(const f32x4*)(qb + c);
    a += r4*q4;
  }
  float s = a[0]+a[1]+a[2]+a[3];
  #pragma unroll
  for (int m=1;m<64;m<<=1) s += __shfl_xor(s, m);
  if (lane == 0) sc[b*132 + jj] = s + b_a[0];
}

// ---------- softmax * gauss ----------
__global__ void k_softmax(const float* __restrict__ sc, const int* __restrict__ s_i,
                          const float* __restrict__ p_t, float* __restrict__ a_t){
  int b = blockIdx.x, l = threadIdx.x;
  const float* scb = sc + b*132;
  float mx = -1e30f;
  for (int j=l; j<129; j+=64) mx = fmaxf(mx, scb[j]);
  #pragma unroll
  for (int m=1;m<64;m<<=1) mx = fmaxf(mx, __shfl_xor(mx, m));
  float sum = 0.f;
  for (int j=l; j<129; j+=64) sum += expf(scb[j] - mx);
  #pragma unroll
  for (int m=1;m<64;m<<=1) sum += __shfl_xor(sum, m);
  float inv = 1.0f/sum;
  float pt = p_t[b]; float s0 = (float)(s_i[b] - 64);
  for (int j=l; j<129; j+=64){
    float e = expf(scb[j]-mx)*inv;
    float d = (s0 + (float)j) - pt;
    a_t[b*132 + j] = e * expf(-(d*d) * (1.0f/2048.0f));
  }
}

// ---------- context: 1 block per b, 4 waves split the j-loop ----------
__global__ __launch_bounds__(256) void k_context(
    const float* __restrict__ a_t, const float* __restrict__ h_s,
    const int* __restrict__ s_i, const float* __restrict__ h,
    float* __restrict__ ctx_out, __bf16* __restrict__ A0, __bf16* __restrict__ A1){
  __shared__ float sat[132];
  __shared__ float sctx[4][1024];
  int b = blockIdx.x, t = threadIdx.x;
  int w = t >> 6, l = t & 63;
  if (t < 129) sat[t] = a_t[b*132 + t];
  __syncthreads();
  int pos0 = s_i[b] - 64;
  int jstart = (w == 0) ? 0 : (33 + 32*(w-1));
  int jcnt   = (w == 0) ? 33 : 32;
  const float* base = h_s + ((size_t)pos0*BB + b)*HH;
  f32x4 acc[4];
  #pragma unroll
  for (int qq=0;qq<4;++qq) acc[qq] = f32x4{0.f,0.f,0.f,0.f};
  for (int j = jstart; j < jstart + jcnt; ++j){
    const float* row = base + (size_t)j*BB*HH;
    float aj = sat[j];
    #pragma unroll
    for (int qq=0;qq<4;++qq){
      f32x4 r = *(const f32x4*)(row + qq*256 + l*4);
      acc[qq] += r * aj;
    }
  }
  #pragma unroll
  for (int qq=0;qq<4;++qq)
    *(f32x4*)(&sctx[w][qq*256 + l*4]) = acc[qq];
  __syncthreads();
  int c = t*4;
  f32x4 v = *(f32x4*)(&sctx[0][c]) + *(f32x4*)(&sctx[1][c])
          + *(f32x4*)(&sctx[2][c]) + *(f32x4*)(&sctx[3][c]);
  *(f32x4*)(ctx_out + (size_t)b*HH + c) = v;
  f32x4 h0 = *(const f32x4*)(h + (size_t)b*HH + c) + v;
  f32x4 h1 = *(const f32x4*)(h + (size_t)BB*HH + (size_t)b*HH + c) + v;
  bf16_4 v0, v1;
  #pragma unroll
  for (int i=0;i<4;i++){ v0[i]=(__bf16)h0[i]; v1[i]=(__bf16)h1[i]; }
  *(bf16_4*)(A0 + (size_t)b*2048 + 1024 + c) = v0;
  *(bf16_4*)(A1 + (size_t)b*2048 + 1024 + c) = v1;
}

// ---------- LSTM cell ----------
__global__ void k_cell(const float* __restrict__ gates, const float* __restrict__ c_in,
                       float* __restrict__ h_out, float* __restrict__ c_out,
                       __bf16* __restrict__ Anext, int strideNext){
  int g = blockIdx.x*256 + threadIdx.x;
  int b = g >> 10, hc = g & 1023;
  const float* gb = gates + (size_t)b*4096;
  float ig = gb[hc], fg = gb[1024+hc], gg = gb[2048+hc], og = gb[3072+hc];
  float cn = sigmoidf_(fg)*c_in[g] + sigmoidf_(ig)*tanhf(gg);
  float hn = sigmoidf_(og)*tanhf(cn);
  c_out[g] = cn; h_out[g] = hn;
  Anext[(size_t)b*strideNext + hc] = (__bf16)hn;
}

// ---------- lse from partials ----------
__global__ void k_lse2(const float* __restrict__ Pmax, const float* __restrict__ Psum,
                       float* __restrict__ lse){
  int b = blockIdx.x, l = threadIdx.x;   // 64 threads
  float M = -1e30f;
  for (int i=l; i<250; i+=64) M = fmaxf(M, Pmax[(size_t)i*128 + b]);
  #pragma unroll
  for (int m=1;m<64;m<<=1) M = fmaxf(M, __shfl_xor(M, m));
  float s = 0.f;
  for (int i=l; i<250; i+=64) s += Psum[(size_t)i*128 + b] * expf(Pmax[(size_t)i*128 + b] - M);
  #pragma unroll
  for (int m=1;m<64;m<<=1) s += __shfl_xor(s, m);
  if (l == 0) lse[b] = M + logf(s);
}

// ---------- in-place subtract lse ----------
__global__ void k_sub(float* __restrict__ out, const float* __restrict__ lse){
  int b = blockIdx.y;
  int i = blockIdx.x*256 + threadIdx.x*4;
  float L = lse[b];
  f32x4 v = *(f32x4*)(out + (size_t)b*VV + i);
  v[0]-=L; v[1]-=L; v[2]-=L; v[3]-=L;
  *(f32x4*)(out + (size_t)b*VV + i) = v;
}

// ---------- launch ----------
extern "C" void kernel_launch(void* const* d_in, const int* in_sizes, int n_in,
                              void* d_out, int out_size, void* d_ws, size_t ws_size,
                              hipStream_t stream){
  const int*   ids   = (const int*)d_in[0];
  const float* h     = (const float*)d_in[1];
  const float* c     = (const float*)d_in[2];
  const float* h_s   = (const float*)d_in[3];
  const float* emb   = (const float*)d_in[4];
  const float* W_pt  = (const float*)d_in[5];
  const float* b_pt  = (const float*)d_in[6];
  const float* v_pt  = (const float*)d_in[7];
  const float* b_v   = (const float*)d_in[8];
  const float* W_a   = (const float*)d_in[9];
  const float* b_a   = (const float*)d_in[10];
  const float* W_ih  = (const float*)d_in[11];
  const float* W_hh  = (const float*)d_in[12];
  const float* b_ih  = (const float*)d_in[13];
  const float* b_hh  = (const float*)d_in[14];
  const float* W_out = (const float*)d_in[15];
  const float* b_out = (const float*)d_in[16];

  char* ws = (char*)d_ws;
  __bf16* A0   = (__bf16*)(ws + OFF_A0);
  __bf16* A1   = (__bf16*)(ws + OFF_A1);
  __bf16* Alog = (__bf16*)(ws + OFF_ALOG);
  __bf16* Ah   = (__bf16*)(ws + OFF_AH);
  __bf16* Am   = (__bf16*)(ws + OFF_AM);
  __bf16* Al   = (__bf16*)(ws + OFF_AL);
  float* WaT   = (float*)(ws + OFF_WAT);
  float* q     = (float*)(ws + OFF_Q);
  float* z     = (float*)(ws + OFF_Z);
  float* p_t   = (float*)(ws + OFF_PT);
  int*   s_i   = (int*)  (ws + OFF_SI);
  float* sc    = (float*)(ws + OFF_SC);
  float* a_t   = (float*)(ws + OFF_AT);
  float* g0    = (float*)(ws + OFF_G0);
  float* g1    = (float*)(ws + OFF_G1);
  float* Pmax  = (float*)(ws + OFF_PMAX);
  float* Psum  = (float*)(ws + OFF_PSUM);
  float* lse   = (float*)(ws + OFF_LSE);

  float* out        = (float*)d_out;
  float* out_logits = out;
  float* out_h      = out + 4096000;
  float* out_c      = out + 4358144;
  float* out_ctx    = out + 4620288;
  float* out_s      = out + 4751360;

  k_transpose<<<dim3(32,32), 256, 0, stream>>>(W_a, WaT);
  k_prep<<<256, 256, 0, stream>>>(ids, emb, h, b_pt, b_ih, b_hh, A0, Ah, Am, Al, z, q, g0, g1);
  // q = h_top @ W_a  (2-way split, K-split x4, atomic accumulate)
  k_gemm<2,3><<<dim3(8,4), 256, 0, stream>>>(Ah, Am, nullptr, 1024, WaT, nullptr, 1024, 0,
                                             nullptr, q, 1024, nullptr, nullptr);
  // z = h_top @ W_pt^T + b_pt  (3-way split, K-split x4)
  k_gemm<3,3><<<dim3(8,4), 256, 0, stream>>>(Ah, Am, Al, 1024, W_pt, nullptr, 1024, 0,
                                             nullptr, z, 1024, nullptr, nullptr);
  k_s2<<<128, 256, 0, stream>>>(z, v_pt, b_v, p_t, s_i, out_s);
  k_scores<<<dim3(128, 33), 256, 0, stream>>>(q, h_s, s_i, b_a, sc);
  k_softmax<<<128, 64, 0, stream>>>(sc, s_i, p_t, a_t);
  k_context<<<128, 256, 0, stream>>>(a_t, h_s, s_i, h, out_ctx, A0, A1);
  // layer 0 gates (K-split x4, bias pre-initialized)
  k_gemm<1,3><<<dim3(32,4), 256, 0, stream>>>(A0, nullptr, nullptr, 2048, W_ih, W_hh, 1024, 1024,
                                              nullptr, g0, 4096, nullptr, nullptr);
  k_cell<<<512, 256, 0, stream>>>(g0, c, out_h, out_c, A1, 2048);
  // layer 1 gates
  k_gemm<1,3><<<dim3(32,4), 256, 0, stream>>>(A1, nullptr, nullptr, 2048, W_ih + 4194304, W_hh + 4194304,
                                              1024, 1024, nullptr, g1, 4096, nullptr, nullptr);
  k_cell<<<512, 256, 0, stream>>>(g1, c + 131072, out_h + 131072, out_c + 131072, Alog, 1024);
  // logits GEMM with fused log-softmax partials, writes directly to d_out
  k_gemm<1,2><<<dim3(250,1), 256, 0, stream>>>(Alog, nullptr, nullptr, 1024, W_out, nullptr, 1024, 0,
                                               b_out, out_logits, 32000, Pmax, Psum);
  k_lse2<<<128, 64, 0, stream>>>(Pmax, Psum, lse);
  k_sub<<<dim3(125,128), 64, 0, stream>>>(out_logits, lse);
}